// Round 5
// baseline (862.250 us; speedup 1.0000x reference)
//
#include <hip/hip_runtime.h>

#define BD  16    // batch size, fixed by problem
#define NPB 1024  // nodes per bucket (power of 2)
#define EPB 2048  // edges per partition block
#define CAP 5120  // LDS staging capacity per bucket (avg ~4090 edges, +16 sigma)

typedef float f4v __attribute__((ext_vector_type(4)));

// ---- Pass A: per-(block k, bucket b) histogram: cnt[k*NB + b] ---------------
__global__ void passA_k(const int* __restrict__ ei, int* __restrict__ cnt,
                        int E, int NB) {
    __shared__ int h[512];           // NB <= 512
    int t = threadIdx.x, k = blockIdx.x;
    for (int b = t; b < NB; b += 256) h[b] = 0;
    __syncthreads();
    int eb = k * EPB;
#pragma unroll
    for (int r = 0; r < EPB / 256; ++r) {
        int e = eb + r * 256 + t;
        if (e < E) atomicAdd(&h[ei[e] >> 10], 1);
    }
    __syncthreads();
    for (int b = t; b < NB; b += 256) cnt[(size_t)k * NB + b] = h[b];
}

// ---- Pass B1: tot[b] = sum_k cnt[k][b] --------------------------------------
__global__ void passB1_k(const int* __restrict__ cnt, int* __restrict__ tot,
                         int K, int NB) {
    __shared__ int s[256];
    int t = threadIdx.x, b = blockIdx.x;
    int acc = 0;
    for (int k = t; k < K; k += 256) acc += cnt[(size_t)k * NB + b];
    s[t] = acc;
    __syncthreads();
    for (int off = 128; off > 0; off >>= 1) {
        if (t < off) s[t] += s[t + off];
        __syncthreads();
    }
    if (t == 0) tot[b] = s[0];
}

// ---- Pass B2: base = exclusive scan of tot; base[NB] = E --------------------
__global__ void passB2_k(const int* __restrict__ tot, int* __restrict__ base,
                         int NB, int E) {
    __shared__ int s[512];
    int t = threadIdx.x;
    s[t] = (t < NB) ? tot[t] : 0;
    __syncthreads();
    for (int off = 1; off < 512; off <<= 1) {
        int v = (t >= off) ? s[t - off] : 0;
        __syncthreads();
        s[t] += v;
        __syncthreads();
    }
    if (t < NB) base[t] = (t == 0) ? 0 : s[t - 1];
    if (t == 0) base[NB] = E;
}

// ---- Pass B3: per-bucket exclusive scan across blocks (in-place) ------------
__global__ void passB3_k(int* __restrict__ cnt, const int* __restrict__ base,
                         int K, int NB) {
    __shared__ int s[256];
    int t = threadIdx.x, b = blockIdx.x;
    int k0 = t * 4;
    int e0 = 0, e1 = 0, e2 = 0, e3 = 0;
    if (k0 + 0 < K) e0 = cnt[(size_t)(k0 + 0) * NB + b];
    if (k0 + 1 < K) e1 = cnt[(size_t)(k0 + 1) * NB + b];
    if (k0 + 2 < K) e2 = cnt[(size_t)(k0 + 2) * NB + b];
    if (k0 + 3 < K) e3 = cnt[(size_t)(k0 + 3) * NB + b];
    s[t] = e0 + e1 + e2 + e3;
    __syncthreads();
    for (int off = 1; off < 256; off <<= 1) {
        int v = (t >= off) ? s[t - off] : 0;
        __syncthreads();
        s[t] += v;
        __syncthreads();
    }
    int run = base[b] + ((t == 0) ? 0 : s[t - 1]);
    if (k0 + 0 < K) { cnt[(size_t)(k0 + 0) * NB + b] = run; run += e0; }
    if (k0 + 1 < K) { cnt[(size_t)(k0 + 1) * NB + b] = run; run += e1; }
    if (k0 + 2 < K) { cnt[(size_t)(k0 + 2) * NB + b] = run; run += e2; }
    if (k0 + 3 < K) { cnt[(size_t)(k0 + 3) * NB + b] = run; run += e3; }
}

// ---- Pass C: partition edges into bucket-grouped COO ------------------------
__global__ void passC_k(const int* __restrict__ ei, const float* __restrict__ ea,
                        const float* __restrict__ vel, const float* __restrict__ dp,
                        const int* __restrict__ cnt, int2* __restrict__ cobuf,
                        int E, int NB) {
    __shared__ int cur[512];
    int t = threadIdx.x, k = blockIdx.x;
    for (int b = t; b < NB; b += 256) cur[b] = cnt[(size_t)k * NB + b];
    __syncthreads();
    float v0 = vel[0], v1 = vel[1];
    float d = dp[0]; d *= d;
    int eb = k * EPB;
#pragma unroll
    for (int r = 0; r < EPB / 256; ++r) {
        int e = eb + r * 256 + t;
        if (e < E) {
            int i = ei[e];
            int j = ei[(size_t)E + e];
            float2 a = ((const float2*)ea)[e];
            float cj = -0.5f * (a.x * v0 + a.y * v1) + d;
            int pos = atomicAdd(&cur[i >> 10], 1);
            cobuf[pos] = make_int2(((i & (NPB - 1)) << 19) | j, __float_as_int(cj));
        }
    }
}

// ---- Pass D: per-bucket CSR build in LDS; emits cc, rp, sci -----------------
__global__ void __launch_bounds__(256) passD_k(
        const int2* __restrict__ cobuf, const int* __restrict__ base,
        const float* __restrict__ dp,
        int2* __restrict__ cc, int* __restrict__ rp, float* __restrict__ sci,
        int N, int NB) {
    __shared__ int  deg[NPB];
    __shared__ int  lrp[NPB + 1];
    __shared__ int  cur[NPB];
    __shared__ int2 sc[CAP];
    __shared__ int  ssum[256];
    int t = threadIdx.x, b = blockIdx.x;
    int n0 = b << 10;
    int nn = min(NPB, N - n0);
    int start = base[b], end = base[b + 1];
    int m = end - start;

    for (int l = t; l < NPB; l += 256) deg[l] = 0;
    __syncthreads();
    for (int p = start + t; p < end; p += 256)
        atomicAdd(&deg[cobuf[p].x >> 19], 1);
    __syncthreads();

    int l0 = t * 4;
    int d0 = deg[l0], d1 = deg[l0 + 1], d2 = deg[l0 + 2], d3 = deg[l0 + 3];
    ssum[t] = d0 + d1 + d2 + d3;
    __syncthreads();
    for (int off = 1; off < 256; off <<= 1) {
        int v = (t >= off) ? ssum[t - off] : 0;
        __syncthreads();
        ssum[t] += v;
        __syncthreads();
    }
    int ex = (t == 0) ? 0 : ssum[t - 1];
    lrp[l0 + 0] = ex;
    lrp[l0 + 1] = ex + d0;
    lrp[l0 + 2] = ex + d0 + d1;
    lrp[l0 + 3] = ex + d0 + d1 + d2;
    if (t == 255) lrp[NPB] = ssum[255];
    __syncthreads();

    for (int l = t; l < NPB; l += 256) cur[l] = lrp[l];
    for (int l = t; l < nn; l += 256) rp[n0 + l] = start + lrp[l];
    if (b == NB - 1 && t == 0) rp[N] = start + m;
    __syncthreads();

    bool fits = (m <= CAP);
    if (fits) {
        for (int p = start + t; p < end; p += 256) {
            int2 w = cobuf[p];
            int il = w.x >> 19;
            int q = atomicAdd(&cur[il], 1);
            sc[q] = make_int2(w.x & 0x7FFFF, w.y);
        }
        __syncthreads();
        for (int q = t; q < m; q += 256) cc[start + q] = sc[q];
    } else {
        for (int p = start + t; p < end; p += 256) {
            int2 w = cobuf[p];
            int il = w.x >> 19;
            int q = atomicAdd(&cur[il], 1);
            cc[start + q] = make_int2(w.x & 0x7FFFF, w.y);
        }
        __syncthreads();
    }

    float d = dp[0]; d *= d;
    for (int l = t; l < nn; l += 256) {
        int qa = lrp[l], qb = lrp[l + 1];
        float s = 0.f;
        if (fits) { for (int q = qa; q < qb; ++q) s += __int_as_float(sc[q].y); }
        else      { for (int q = qa; q < qb; ++q) s += __int_as_float(cc[start + q].y); }
        sci[n0 + l] = s - 2.f * d * (float)(qb - qa);
    }
}

// ======================== transposes [B,N] <-> [N,B] ========================

__global__ void tin_k(const float* __restrict__ x, float* __restrict__ h, int N) {
    int n = blockIdx.x * blockDim.x + threadIdx.x;
    if (n >= N) return;
    float v[BD];
#pragma unroll
    for (int b = 0; b < BD; ++b) v[b] = x[(size_t)b * N + n];
    float4* dst = (float4*)(h + (size_t)n * BD);
#pragma unroll
    for (int q = 0; q < 4; ++q) dst[q] = make_float4(v[4*q], v[4*q+1], v[4*q+2], v[4*q+3]);
}

__global__ void tout_k(const float* __restrict__ h, float* __restrict__ x, int N) {
    int n = blockIdx.x * blockDim.x + threadIdx.x;
    if (n >= N) return;
    const float4* src = (const float4*)(h + (size_t)n * BD);
    float v[BD];
#pragma unroll
    for (int q = 0; q < 4; ++q) { float4 t = src[q]; v[4*q]=t.x; v[4*q+1]=t.y; v[4*q+2]=t.z; v[4*q+3]=t.w; }
#pragma unroll
    for (int b = 0; b < BD; ++b) x[(size_t)b * N + n] = v[b];
}

// ====================== per-step gather (no atomics) ========================
// 4 lanes per node; lane q owns floats [4q,4q+4) of the node's 16-wide row.
// Uniform masked 4-wide loop (no serial remainder); cc NT-loaded, hn NT-stored.
#define FMA4(acc, cj, g) \
    acc.x = fmaf(cj, g.x, acc.x); acc.y = fmaf(cj, g.y, acc.y); \
    acc.z = fmaf(cj, g.z, acc.z); acc.w = fmaf(cj, g.w, acc.w);

__global__ void step_k(const int* __restrict__ rp, const long long* __restrict__ cc,
                       const float* __restrict__ sci, const float* __restrict__ hc,
                       float* __restrict__ hn, int N) {
    unsigned gid = blockIdx.x * blockDim.x + threadIdx.x;
    unsigned n = gid >> 2;
    if (n >= (unsigned)N) return;
    unsigned s = (gid & 3u) * 4u;
    const float* hcs = hc + s;
    float4 h0 = *(const float4*)(hcs + (size_t)n * BD);
    float sc = sci[n];
    float4 a0, a1, a2, a3;
    a0.x = fmaf(sc, h0.x, h0.x);   // h * (1 + Sci)
    a0.y = fmaf(sc, h0.y, h0.y);
    a0.z = fmaf(sc, h0.z, h0.z);
    a0.w = fmaf(sc, h0.w, h0.w);
    a1 = make_float4(0.f, 0.f, 0.f, 0.f);
    a2 = make_float4(0.f, 0.f, 0.f, 0.f);
    a3 = make_float4(0.f, 0.f, 0.f, 0.f);
    int b = rp[n], e2 = rp[n + 1];
    for (int p = b; p < e2; p += 4) {
        // uniform 4-wide iteration: clamp index to p (in-bounds), zero the coef
        int i1 = (p + 1 < e2) ? p + 1 : p;
        int i2 = (p + 2 < e2) ? p + 2 : p;
        int i3 = (p + 3 < e2) ? p + 3 : p;
        long long v0 = __builtin_nontemporal_load(cc + p);
        long long v1 = __builtin_nontemporal_load(cc + i1);
        long long v2 = __builtin_nontemporal_load(cc + i2);
        long long v3 = __builtin_nontemporal_load(cc + i3);
        int t0 = (int)(unsigned)v0, t1 = (int)(unsigned)v1;
        int t2 = (int)(unsigned)v2, t3 = (int)(unsigned)v3;
        float j0 = __int_as_float((int)(v0 >> 32));
        float j1 = (p + 1 < e2) ? __int_as_float((int)(v1 >> 32)) : 0.f;
        float j2 = (p + 2 < e2) ? __int_as_float((int)(v2 >> 32)) : 0.f;
        float j3 = (p + 3 < e2) ? __int_as_float((int)(v3 >> 32)) : 0.f;
        float4 g0 = *(const float4*)(hcs + (size_t)t0 * BD);
        float4 g1 = *(const float4*)(hcs + (size_t)t1 * BD);
        float4 g2 = *(const float4*)(hcs + (size_t)t2 * BD);
        float4 g3 = *(const float4*)(hcs + (size_t)t3 * BD);
        FMA4(a0, j0, g0);
        FMA4(a1, j1, g1);
        FMA4(a2, j2, g2);
        FMA4(a3, j3, g3);
    }
    a0.x += a1.x + a2.x + a3.x;
    a0.y += a1.y + a2.y + a3.y;
    a0.z += a1.z + a2.z + a3.z;
    a0.w += a1.w + a2.w + a3.w;
    f4v out;
    out[0] = a0.x; out[1] = a0.y; out[2] = a0.z; out[3] = a0.w;
    __builtin_nontemporal_store(out, (f4v*)(hn + (size_t)n * BD + s));
}

// ============================================================================

extern "C" void kernel_launch(void* const* d_in, const int* in_sizes, int n_in,
                              void* d_out, int out_size, void* d_ws, size_t ws_size,
                              hipStream_t stream) {
    const float* x   = (const float*)d_in[0];
    const int*   ei  = (const int*)  d_in[1];
    const float* ea  = (const float*)d_in[2];
    const float* vel = (const float*)d_in[3];
    const float* dp  = (const float*)d_in[4];

    const int N = in_sizes[0] / BD;  // 500000
    const int E = in_sizes[1] / 2;   // 2000000
    const int T = 16;

    const int K  = (E + EPB - 1) / EPB;   // partition blocks (977)
    const int NB = (N + NPB - 1) / NPB;   // buckets (489), must be <= 512

    char* ws = (char*)d_ws;
    size_t off = 0;
    int2*  cc   = (int2*)(ws + off);  off += (size_t)E * 8;
    int*   rp   = (int*) (ws + off);  off += (size_t)(N + 1) * 4;
    float* sci  = (float*)(ws + off); off += (size_t)N * 4;
    int*   cnt  = (int*) (ws + off);  off += (size_t)K * NB * 4;
    int*   tot  = (int*) (ws + off);  off += (size_t)NB * 4;
    int*   base = (int*) (ws + off);  off += (size_t)(NB + 1) * 4;
    off = (off + 255) & ~(size_t)255;
    float* hA   = (float*)(ws + off);
    int2*  cobuf = (int2*)hA;        // 16 MB, dead before tin_k runs
    float* hB   = (float*)d_out;     // second ping-pong buffer; T even -> final in hA

    passA_k <<<K, 256, 0, stream>>>(ei, cnt, E, NB);
    passB1_k<<<NB, 256, 0, stream>>>(cnt, tot, K, NB);
    passB2_k<<<1, 512, 0, stream>>>(tot, base, NB, E);
    passB3_k<<<NB, 256, 0, stream>>>(cnt, base, K, NB);
    passC_k <<<K, 256, 0, stream>>>(ei, ea, vel, dp, cnt, cobuf, E, NB);
    passD_k <<<NB, 256, 0, stream>>>(cobuf, base, dp, cc, rp, sci, N, NB);

    tin_k<<<(N + 255) / 256, 256, 0, stream>>>(x, hA, N);

    float* cur = hA;
    float* nxt = hB;
    for (int t = 0; t < T; ++t) {
        step_k<<<((size_t)N * 4 + 255) / 256, 256, 0, stream>>>(rp, (const long long*)cc, sci, cur, nxt, N);
        float* tmp = cur; cur = nxt; nxt = tmp;
    }
    tout_k<<<(N + 255) / 256, 256, 0, stream>>>(cur, (float*)d_out, N);
}

// Round 6
// 814.482 us; speedup vs baseline: 1.0586x; 1.0586x over previous
//
#include <hip/hip_runtime.h>

#define BD  16    // batch size, fixed by problem
#define NPB 1024  // nodes per bucket (power of 2)
#define EPB 8192  // edges per partition block (long runs -> good passC line use)
#define CAP 5120  // LDS staging capacity per bucket (avg ~4090 edges, +16 sigma)

// ---- Pass A: per-(block k, bucket b) histogram: cnt[k*NB + b] ---------------
__global__ void passA_k(const int* __restrict__ ei, int* __restrict__ cnt,
                        int E, int NB) {
    __shared__ int h[512];           // NB <= 512
    int t = threadIdx.x, k = blockIdx.x;
    for (int b = t; b < NB; b += 256) h[b] = 0;
    __syncthreads();
    int eb = k * EPB;
    for (int r = 0; r < EPB / 256; ++r) {
        int e = eb + r * 256 + t;
        if (e < E) atomicAdd(&h[ei[e] >> 10], 1);
    }
    __syncthreads();
    for (int b = t; b < NB; b += 256) cnt[(size_t)k * NB + b] = h[b];
}

// ---- Pass B1: tot[b] = sum_k cnt[k][b] --------------------------------------
__global__ void passB1_k(const int* __restrict__ cnt, int* __restrict__ tot,
                         int K, int NB) {
    __shared__ int s[256];
    int t = threadIdx.x, b = blockIdx.x;
    int acc = 0;
    for (int k = t; k < K; k += 256) acc += cnt[(size_t)k * NB + b];
    s[t] = acc;
    __syncthreads();
    for (int off = 128; off > 0; off >>= 1) {
        if (t < off) s[t] += s[t + off];
        __syncthreads();
    }
    if (t == 0) tot[b] = s[0];
}

// ---- Pass B2: base = exclusive scan of tot; base[NB] = E --------------------
__global__ void passB2_k(const int* __restrict__ tot, int* __restrict__ base,
                         int NB, int E) {
    __shared__ int s[512];
    int t = threadIdx.x;
    s[t] = (t < NB) ? tot[t] : 0;
    __syncthreads();
    for (int off = 1; off < 512; off <<= 1) {
        int v = (t >= off) ? s[t - off] : 0;
        __syncthreads();
        s[t] += v;
        __syncthreads();
    }
    if (t < NB) base[t] = (t == 0) ? 0 : s[t - 1];
    if (t == 0) base[NB] = E;
}

// ---- Pass B3: per-bucket exclusive scan across blocks (in-place) ------------
__global__ void passB3_k(int* __restrict__ cnt, const int* __restrict__ base,
                         int K, int NB) {
    __shared__ int s[256];
    int t = threadIdx.x, b = blockIdx.x;
    int k0 = t * 4;
    int e0 = 0, e1 = 0, e2 = 0, e3 = 0;
    if (k0 + 0 < K) e0 = cnt[(size_t)(k0 + 0) * NB + b];
    if (k0 + 1 < K) e1 = cnt[(size_t)(k0 + 1) * NB + b];
    if (k0 + 2 < K) e2 = cnt[(size_t)(k0 + 2) * NB + b];
    if (k0 + 3 < K) e3 = cnt[(size_t)(k0 + 3) * NB + b];
    s[t] = e0 + e1 + e2 + e3;
    __syncthreads();
    for (int off = 1; off < 256; off <<= 1) {
        int v = (t >= off) ? s[t - off] : 0;
        __syncthreads();
        s[t] += v;
        __syncthreads();
    }
    int run = base[b] + ((t == 0) ? 0 : s[t - 1]);
    if (k0 + 0 < K) { cnt[(size_t)(k0 + 0) * NB + b] = run; run += e0; }
    if (k0 + 1 < K) { cnt[(size_t)(k0 + 1) * NB + b] = run; run += e1; }
    if (k0 + 2 < K) { cnt[(size_t)(k0 + 2) * NB + b] = run; run += e2; }
    if (k0 + 3 < K) { cnt[(size_t)(k0 + 3) * NB + b] = run; run += e3; }
}

// ---- Pass C: partition edges into bucket-grouped COO ------------------------
__global__ void passC_k(const int* __restrict__ ei, const float* __restrict__ ea,
                        const float* __restrict__ vel, const float* __restrict__ dp,
                        const int* __restrict__ cnt, int2* __restrict__ cobuf,
                        int E, int NB) {
    __shared__ int cur[512];
    int t = threadIdx.x, k = blockIdx.x;
    for (int b = t; b < NB; b += 256) cur[b] = cnt[(size_t)k * NB + b];
    __syncthreads();
    float v0 = vel[0], v1 = vel[1];
    float d = dp[0]; d *= d;
    int eb = k * EPB;
    for (int r = 0; r < EPB / 256; ++r) {
        int e = eb + r * 256 + t;
        if (e < E) {
            int i = ei[e];
            int j = ei[(size_t)E + e];
            float2 a = ((const float2*)ea)[e];
            float cj = -0.5f * (a.x * v0 + a.y * v1) + d;
            int pos = atomicAdd(&cur[i >> 10], 1);
            cobuf[pos] = make_int2(((i & (NPB - 1)) << 19) | j, __float_as_int(cj));
        }
    }
}

// ---- Pass D: per-bucket CSR build in LDS; emits cc, rp, sci -----------------
__global__ void __launch_bounds__(256) passD_k(
        const int2* __restrict__ cobuf, const int* __restrict__ base,
        const float* __restrict__ dp,
        int2* __restrict__ cc, int* __restrict__ rp, float* __restrict__ sci,
        int N, int NB) {
    __shared__ int  deg[NPB];
    __shared__ int  lrp[NPB + 1];
    __shared__ int  cur[NPB];
    __shared__ int2 sc[CAP];
    __shared__ int  ssum[256];
    int t = threadIdx.x, b = blockIdx.x;
    int n0 = b << 10;
    int nn = min(NPB, N - n0);
    int start = base[b], end = base[b + 1];
    int m = end - start;

    for (int l = t; l < NPB; l += 256) deg[l] = 0;
    __syncthreads();
    for (int p = start + t; p < end; p += 256)
        atomicAdd(&deg[cobuf[p].x >> 19], 1);
    __syncthreads();

    int l0 = t * 4;
    int d0 = deg[l0], d1 = deg[l0 + 1], d2 = deg[l0 + 2], d3 = deg[l0 + 3];
    ssum[t] = d0 + d1 + d2 + d3;
    __syncthreads();
    for (int off = 1; off < 256; off <<= 1) {
        int v = (t >= off) ? ssum[t - off] : 0;
        __syncthreads();
        ssum[t] += v;
        __syncthreads();
    }
    int ex = (t == 0) ? 0 : ssum[t - 1];
    lrp[l0 + 0] = ex;
    lrp[l0 + 1] = ex + d0;
    lrp[l0 + 2] = ex + d0 + d1;
    lrp[l0 + 3] = ex + d0 + d1 + d2;
    if (t == 255) lrp[NPB] = ssum[255];
    __syncthreads();

    for (int l = t; l < NPB; l += 256) cur[l] = lrp[l];
    for (int l = t; l < nn; l += 256) rp[n0 + l] = start + lrp[l];
    if (b == NB - 1 && t == 0) rp[N] = start + m;
    __syncthreads();

    bool fits = (m <= CAP);
    if (fits) {
        for (int p = start + t; p < end; p += 256) {
            int2 w = cobuf[p];
            int il = w.x >> 19;
            int q = atomicAdd(&cur[il], 1);
            sc[q] = make_int2(w.x & 0x7FFFF, w.y);
        }
        __syncthreads();
        for (int q = t; q < m; q += 256) cc[start + q] = sc[q];
    } else {
        for (int p = start + t; p < end; p += 256) {
            int2 w = cobuf[p];
            int il = w.x >> 19;
            int q = atomicAdd(&cur[il], 1);
            cc[start + q] = make_int2(w.x & 0x7FFFF, w.y);
        }
        __syncthreads();
    }

    float d = dp[0]; d *= d;
    for (int l = t; l < nn; l += 256) {
        int qa = lrp[l], qb = lrp[l + 1];
        float s = 0.f;
        if (fits) { for (int q = qa; q < qb; ++q) s += __int_as_float(sc[q].y); }
        else      { for (int q = qa; q < qb; ++q) s += __int_as_float(cc[start + q].y); }
        sci[n0 + l] = s - 2.f * d * (float)(qb - qa);
    }
}

// ======================== transposes [B,N] <-> [N,B] ========================

__global__ void tin_k(const float* __restrict__ x, float* __restrict__ h, int N) {
    int n = blockIdx.x * blockDim.x + threadIdx.x;
    if (n >= N) return;
    float v[BD];
#pragma unroll
    for (int b = 0; b < BD; ++b) v[b] = x[(size_t)b * N + n];
    float4* dst = (float4*)(h + (size_t)n * BD);
#pragma unroll
    for (int q = 0; q < 4; ++q) dst[q] = make_float4(v[4*q], v[4*q+1], v[4*q+2], v[4*q+3]);
}

__global__ void tout_k(const float* __restrict__ h, float* __restrict__ x, int N) {
    int n = blockIdx.x * blockDim.x + threadIdx.x;
    if (n >= N) return;
    const float4* src = (const float4*)(h + (size_t)n * BD);
    float v[BD];
#pragma unroll
    for (int q = 0; q < 4; ++q) { float4 t = src[q]; v[4*q]=t.x; v[4*q+1]=t.y; v[4*q+2]=t.z; v[4*q+3]=t.w; }
#pragma unroll
    for (int b = 0; b < BD; ++b) x[(size_t)b * N + n] = v[b];
}

// ====================== per-step gather (no atomics) ========================
// 4 lanes per node; lane q owns floats [4q,4q+4) of the node's 16-wide row.
// Main loop: lane-split cc loads (lane q loads cc[p+q]) shared via shfl width=4
// -> 5 VMEM instr/iter instead of 8. Serial remainder as in R4 (best known).
#define FMA4(acc, cj, g) \
    acc.x = fmaf(cj, g.x, acc.x); acc.y = fmaf(cj, g.y, acc.y); \
    acc.z = fmaf(cj, g.z, acc.z); acc.w = fmaf(cj, g.w, acc.w);

__global__ void step_k(const int* __restrict__ rp, const int2* __restrict__ cc,
                       const float* __restrict__ sci, const float* __restrict__ hc,
                       float* __restrict__ hn, int N) {
    unsigned gid = blockIdx.x * blockDim.x + threadIdx.x;
    unsigned n = gid >> 2;
    if (n >= (unsigned)N) return;
    unsigned q = gid & 3u;
    unsigned s = q * 4u;
    const float* hcs = hc + s;
    float4 h0 = *(const float4*)(hcs + (size_t)n * BD);
    float sc = sci[n];
    float4 a0, a1, a2, a3;
    a0.x = fmaf(sc, h0.x, h0.x);   // h * (1 + Sci)
    a0.y = fmaf(sc, h0.y, h0.y);
    a0.z = fmaf(sc, h0.z, h0.z);
    a0.w = fmaf(sc, h0.w, h0.w);
    a1 = make_float4(0.f, 0.f, 0.f, 0.f);
    a2 = make_float4(0.f, 0.f, 0.f, 0.f);
    a3 = make_float4(0.f, 0.f, 0.f, 0.f);
    int p = rp[n], e2 = rp[n + 1];
    for (; p + 4 <= e2; p += 4) {
        // lane q loads entry p+q; group shares all 4 via shfl (width 4)
        int2 w = cc[p + q];
        long long wv = (((long long)(unsigned)w.y) << 32) | (unsigned)w.x;
        long long w0 = __shfl(wv, 0, 4);
        long long w1 = __shfl(wv, 1, 4);
        long long w2 = __shfl(wv, 2, 4);
        long long w3 = __shfl(wv, 3, 4);
        int t0 = (int)(unsigned)w0, t1 = (int)(unsigned)w1;
        int t2 = (int)(unsigned)w2, t3 = (int)(unsigned)w3;
        float4 g0 = *(const float4*)(hcs + (size_t)t0 * BD);
        float4 g1 = *(const float4*)(hcs + (size_t)t1 * BD);
        float4 g2 = *(const float4*)(hcs + (size_t)t2 * BD);
        float4 g3 = *(const float4*)(hcs + (size_t)t3 * BD);
        float j0 = __int_as_float((int)(w0 >> 32));
        float j1 = __int_as_float((int)(w1 >> 32));
        float j2 = __int_as_float((int)(w2 >> 32));
        float j3 = __int_as_float((int)(w3 >> 32));
        FMA4(a0, j0, g0);
        FMA4(a1, j1, g1);
        FMA4(a2, j2, g2);
        FMA4(a3, j3, g3);
    }
    for (; p < e2; ++p) {
        int2 c0 = cc[p];
        float4 g0 = *(const float4*)(hcs + (size_t)c0.x * BD);
        float j0 = __int_as_float(c0.y);
        FMA4(a0, j0, g0);
    }
    a0.x += a1.x + a2.x + a3.x;
    a0.y += a1.y + a2.y + a3.y;
    a0.z += a1.z + a2.z + a3.z;
    a0.w += a1.w + a2.w + a3.w;
    *(float4*)(hn + (size_t)n * BD + s) = a0;
}

// ============================================================================

extern "C" void kernel_launch(void* const* d_in, const int* in_sizes, int n_in,
                              void* d_out, int out_size, void* d_ws, size_t ws_size,
                              hipStream_t stream) {
    const float* x   = (const float*)d_in[0];
    const int*   ei  = (const int*)  d_in[1];
    const float* ea  = (const float*)d_in[2];
    const float* vel = (const float*)d_in[3];
    const float* dp  = (const float*)d_in[4];

    const int N = in_sizes[0] / BD;  // 500000
    const int E = in_sizes[1] / 2;   // 2000000
    const int T = 16;

    const int K  = (E + EPB - 1) / EPB;   // partition blocks (245)
    const int NB = (N + NPB - 1) / NPB;   // buckets (489), must be <= 512

    char* ws = (char*)d_ws;
    size_t off = 0;
    int2*  cc   = (int2*)(ws + off);  off += (size_t)E * 8;
    int*   rp   = (int*) (ws + off);  off += (size_t)(N + 1) * 4;
    float* sci  = (float*)(ws + off); off += (size_t)N * 4;
    int*   cnt  = (int*) (ws + off);  off += (size_t)K * NB * 4;
    int*   tot  = (int*) (ws + off);  off += (size_t)NB * 4;
    int*   base = (int*) (ws + off);  off += (size_t)(NB + 1) * 4;
    off = (off + 255) & ~(size_t)255;
    float* hA   = (float*)(ws + off);
    int2*  cobuf = (int2*)hA;        // 16 MB, dead before tin_k runs
    float* hB   = (float*)d_out;     // second ping-pong buffer; T even -> final in hA

    passA_k <<<K, 256, 0, stream>>>(ei, cnt, E, NB);
    passB1_k<<<NB, 256, 0, stream>>>(cnt, tot, K, NB);
    passB2_k<<<1, 512, 0, stream>>>(tot, base, NB, E);
    passB3_k<<<NB, 256, 0, stream>>>(cnt, base, K, NB);
    passC_k <<<K, 256, 0, stream>>>(ei, ea, vel, dp, cnt, cobuf, E, NB);
    passD_k <<<NB, 256, 0, stream>>>(cobuf, base, dp, cc, rp, sci, N, NB);

    tin_k<<<(N + 255) / 256, 256, 0, stream>>>(x, hA, N);

    float* cur = hA;
    float* nxt = hB;
    for (int t = 0; t < T; ++t) {
        step_k<<<((size_t)N * 4 + 255) / 256, 256, 0, stream>>>(rp, cc, sci, cur, nxt, N);
        float* tmp = cur; cur = nxt; nxt = tmp;
    }
    tout_k<<<(N + 255) / 256, 256, 0, stream>>>(cur, (float*)d_out, N);
}